// Round 2
// baseline (558.879 us; speedup 1.0000x reference)
//
#include <hip/hip_runtime.h>
#include <hip/hip_bf16.h>

// HMM forward-backward, B=128, T=1024, K=256.
// P = (diag-offd)*I + offd*J  -> (v@P)[j] = offd*sum(v) + (diag-offd)*v[j].
//
// R4: defeat load sinking. R3's 16-deep register ring was rematerialized away
// by the compiler (VGPR_Count=32 proves it: the ring alone needs 32), so the
// prefetch depth was ~1 and each step ate ~200 cycles of memory latency.
// This version loads y rows through a VOLATILE u64 pointer: volatile VMEM ops
// cannot be sunk, merged, or rematerialized, so the consume-then-refill ring
// is structurally forced. PF=16 keeps the static waitcnt distance (15 loads +
// 16 stores = 31) under the 6-bit vmcnt limit so the compiler emits counted
// vmcnt(31), not clamped/stricter waits.
// Dataflow unchanged from R3 (passing, absmax 0.015625):
//   S_t = cd*R_t + C1[t]*S_{t-1},  R_t = sum_j(y_t * v_{t-1}),
//   C1[t] = offd*sum_j(y_t) precomputed in the sigmoid pass,
//   periodic rescale every 16 steps.

constexpr int BB = 128;
constexpr int TT = 1024;
constexpr int KK = 256;
constexpr int PF = 16;           // prefetch depth (rows == steps)
constexpr size_t YPAD = 8192;    // underread pad for backward prefetch

typedef unsigned long long u64t;

// ---------- DPP wave-64 sum reduction -> broadcast scalar ----------
template <int CTRL, int RM>
__device__ __forceinline__ float dpp_add(float v) {
  int t = __builtin_amdgcn_update_dpp(0, __float_as_int(v), CTRL, RM, 0xf, true);
  return v + __int_as_float(t);
}

__device__ __forceinline__ float wred_dpp(float v) {
  v = dpp_add<0x111, 0xf>(v);  // row_shr:1
  v = dpp_add<0x112, 0xf>(v);  // row_shr:2
  v = dpp_add<0x114, 0xf>(v);  // row_shr:4
  v = dpp_add<0x118, 0xf>(v);  // row_shr:8  -> lane 15 of each row = row sum
  v = dpp_add<0x142, 0xa>(v);  // row_bcast:15
  v = dpp_add<0x143, 0xc>(v);  // row_bcast:31 -> lane63 = total
  return __int_as_float(__builtin_amdgcn_readlane(__float_as_int(v), 63));
}

__device__ __forceinline__ float fsig(float x) {
  return __builtin_amdgcn_rcpf(1.0f + __expf(-x));
}

__device__ __forceinline__ unsigned cvtpk_bf16(float lo, float hi) {
  unsigned r;
  asm("v_cvt_pk_bf16_f32 %0, %1, %2" : "=v"(r) : "v"(lo), "v"(hi));
  return r;  // [15:0]=bf16(lo) [31:16]=bf16(hi), RNE
}
__device__ __forceinline__ float lo16f(unsigned u) { return __uint_as_float(u << 16); }
__device__ __forceinline__ float hi16f(unsigned u) { return __uint_as_float(u & 0xffff0000u); }
__device__ __forceinline__ float bf2f(unsigned short u) {
  return __uint_as_float((unsigned)u << 16);
}

// ---------- pass 0: y = sigmoid(x) bf16 rows + C1[row] = offd*sum(y_row) ----
__global__ __launch_bounds__(256) void sig_pass2(const float* __restrict__ x,
                                                 uint2* __restrict__ y,
                                                 float* __restrict__ C1,
                                                 const float* __restrict__ P) {
  const int lane = threadIdx.x & 63;
  const size_t row = ((size_t)blockIdx.x << 2) | (threadIdx.x >> 6);  // b*TT+t
  const float4 v = reinterpret_cast<const float4*>(x)[row * 64 + lane];
  const unsigned p01 = cvtpk_bf16(fsig(v.x), fsig(v.y));
  const unsigned p23 = cvtpk_bf16(fsig(v.z), fsig(v.w));
  y[row * 64 + lane] = make_uint2(p01, p23);
  // sum the ROUNDED values so C1 matches what the recursion actually uses
  const float s = wred_dpp((lo16f(p01) + hi16f(p01)) + (lo16f(p23) + hi16f(p23)));
  if (lane == 0) C1[row] = P[1] * s;
}

// ---------- pass 1: forward/backward recursions ----------
__global__ __launch_bounds__(64, 1) void hmm_recur2(
    const uint2* __restrict__ y, const float* __restrict__ C1,
    const float* __restrict__ P, const float* __restrict__ p0,
    uint2* __restrict__ alpha, uint2* __restrict__ beta) {
  const int seq = blockIdx.x;   // 0..255
  const int lane = threadIdx.x; // 0..63
  const float diag = P[0];
  const float offd = P[1];
  const float cd = diag - offd;
  const float cod = offd;

  u64t ring[PF];  // slot = row & 15; consume then refill same slot

  if (seq < BB) {
    // ---------------- forward: alpha (unnormalized, periodic rescale) -------
    const int b = seq;
    const uint2* yb = y + (size_t)b * TT * 64;
    // volatile view: loads through this pointer cannot be sunk/remat'd
    const volatile u64t* yq =
        reinterpret_cast<const volatile u64t*>(y) + (size_t)b * TT * 64 + lane;
    uint2* ar = alpha + (size_t)b * TT * 64;
    const float* c1b = C1 + (size_t)b * TT;

    const uint2 yv0 = yb[lane];  // row 0, plain load
#pragma unroll
    for (int i = 0; i < PF; ++i) ring[(1 + i) & 15] = yq[(size_t)(1 + i) * 64];

    const float4 pv = reinterpret_cast<const float4*>(p0)[lane];
    float v0 = pv.x * lo16f(yv0.x), v1 = pv.y * hi16f(yv0.x);
    float v2 = pv.z * lo16f(yv0.y), v3 = pv.w * hi16f(yv0.y);
    float S = wred_dpp((v0 + v1) + (v2 + v3));
    ar[lane] = make_uint2(cvtpk_bf16(v0, v1), cvtpk_bf16(v2, v3));

#define FSTEP(T_, SLOT_, C1V_)                                             \
  {                                                                        \
    const u64t q = ring[SLOT_];                                            \
    ring[SLOT_] = yq[(size_t)((T_) + PF) * 64];                            \
    const unsigned qlo = (unsigned)q, qhi = (unsigned)(q >> 32);           \
    const float y0 = lo16f(qlo), y1 = hi16f(qlo);                          \
    const float y2 = lo16f(qhi), y3 = hi16f(qhi);                          \
    const float R = wred_dpp((y0 * v0 + y1 * v1) + (y2 * v2 + y3 * v3));   \
    const float Sn = cd * R + (C1V_)*S;                                    \
    const float sc = cod * S;                                              \
    v0 = y0 * (cd * v0 + sc); v1 = y1 * (cd * v1 + sc);                    \
    v2 = y2 * (cd * v2 + sc); v3 = y3 * (cd * v3 + sc);                    \
    ar[(size_t)(T_)*64 + lane] =                                           \
        make_uint2(cvtpk_bf16(v0, v1), cvtpk_bf16(v2, v3));                \
    S = Sn;                                                                \
  }

    // peeled: steps t=1..15 (slot = t)
#pragma unroll
    for (int i = 1; i <= 15; ++i) {
      const float c1v = c1b[i];
      FSTEP(i, i & 15, c1v);
    }
    {
      const float rr = __builtin_amdgcn_rcpf(S);
      v0 *= rr; v1 *= rr; v2 *= rr; v3 *= rr; S = 1.0f;
    }

#pragma unroll 1
    for (int g = 1; g < 64; ++g) {   // steps t = 16g .. 16g+15
      const int tb = g * 16;
      float c1g[16];
#pragma unroll
      for (int j = 0; j < 16; ++j) c1g[j] = c1b[tb + j];
#pragma unroll
      for (int i = 0; i < 16; ++i) {  // slot = (tb+i)&15 = i
        FSTEP(tb + i, i, c1g[i]);
      }
      const float rr = __builtin_amdgcn_rcpf(S);
      v0 *= rr; v1 *= rr; v2 *= rr; v3 *= rr; S = 1.0f;
    }
#undef FSTEP
  } else {
    // ---------------- backward: beta (state m = y_{t+1} o beta_{t+1}) ------
    const int b = seq - BB;
    const uint2* yb = y + (size_t)b * TT * 64;
    const volatile u64t* yq =
        reinterpret_cast<const volatile u64t*>(y) + (size_t)b * TT * 64 + lane;
    uint2* br = beta + (size_t)b * TT * 64;
    const float* c1b = C1 + (size_t)b * TT;

    const uint2 yvL = yb[(size_t)(TT - 1) * 64 + lane];  // row 1023, plain
#pragma unroll
    for (int i = 0; i < PF; ++i)
      ring[(1022 - i) & 15] = yq[(size_t)(1022 - i) * 64];

    float m0 = lo16f(yvL.x), m1 = hi16f(yvL.x);
    float m2 = lo16f(yvL.y), m3 = hi16f(yvL.y);
    float S = wred_dpp((m0 + m1) + (m2 + m3));
    br[(size_t)(TT - 1) * 64 + lane] = make_uint2(0x3F803F80u, 0x3F803F80u);

    // step(T): consume y row T, write beta row T; T = 1022 down to 0.
#define BSTEP(T_, SLOT_, C1V_)                                             \
  {                                                                        \
    const u64t q = ring[SLOT_];                                            \
    ring[SLOT_] = yq[(ptrdiff_t)((T_)-PF) * 64];                           \
    const unsigned qlo = (unsigned)q, qhi = (unsigned)(q >> 32);           \
    const float y0 = lo16f(qlo), y1 = hi16f(qlo);                          \
    const float y2 = lo16f(qhi), y3 = hi16f(qhi);                          \
    const float R = wred_dpp((y0 * m0 + y1 * m1) + (y2 * m2 + y3 * m3));   \
    const float Sn = cd * R + (C1V_)*S;                                    \
    const float sc = cod * S;                                              \
    const float h0 = cd * m0 + sc, h1 = cd * m1 + sc;                      \
    const float h2 = cd * m2 + sc, h3 = cd * m3 + sc;                      \
    br[(size_t)(T_)*64 + lane] =                                           \
        make_uint2(cvtpk_bf16(h0, h1), cvtpk_bf16(h2, h3));                \
    m0 = y0 * h0; m1 = y1 * h1; m2 = y2 * h2; m3 = y3 * h3;                \
    S = Sn;                                                                \
  }

    // peeled: T = 1022..1008 (slot = T&15; 1022&15 = 14)
#pragma unroll
    for (int k = 0; k < 15; ++k) {
      const int T = 1022 - k;
      const float c1v = c1b[T];
      BSTEP(T, (1022 - k) & 15, c1v);
    }
    {
      const float rr = __builtin_amdgcn_rcpf(S);
      m0 *= rr; m1 *= rr; m2 *= rr; m3 *= rr; S = 1.0f;
    }

#pragma unroll 1
    for (int g = 1; g < 64; ++g) {   // T = tb .. tb-15, tb = 1007-16(g-1)
      const int tb = 1007 - 16 * (g - 1);
      float c1g[16];
#pragma unroll
      for (int j = 0; j < 16; ++j) c1g[j] = c1b[tb - 15 + j];
#pragma unroll
      for (int i = 0; i < 16; ++i) {  // slot = (tb-i)&15 = 15-i
        BSTEP(tb - i, 15 - i, c1g[15 - i]);
      }
      const float rr = __builtin_amdgcn_rcpf(S);
      m0 *= rr; m1 *= rr; m2 *= rr; m3 *= rr; S = 1.0f;
    }
#undef BSTEP
  }
}

// ---------- pass 2: posterior = normalize(alpha*beta) ----------
__global__ __launch_bounds__(256) void hmm_post(
    const __hip_bfloat16* __restrict__ alpha,
    const __hip_bfloat16* __restrict__ beta, float* __restrict__ out) {
  const size_t gid = (size_t)blockIdx.x * 256 + threadIdx.x;
  const size_t row = gid >> 6;  // one wave per (b,t) row
  const int lane = (int)(gid & 63);
  const ushort4 av = reinterpret_cast<const ushort4*>(alpha)[row * 64 + lane];
  const ushort4 bv = reinterpret_cast<const ushort4*>(beta)[row * 64 + lane];
  const float g0 = bf2f(av.x) * bf2f(bv.x);
  const float g1 = bf2f(av.y) * bf2f(bv.y);
  const float g2 = bf2f(av.z) * bf2f(bv.z);
  const float g3 = bf2f(av.w) * bf2f(bv.w);
  const float s = wred_dpp((g0 + g1) + (g2 + g3));
  const float r = __builtin_amdgcn_rcpf(s);
  float4 o;
  o.x = g0 * r; o.y = g1 * r; o.z = g2 * r; o.w = g3 * r;
  reinterpret_cast<float4*>(out)[row * 64 + lane] = o;
}

extern "C" void kernel_launch(void* const* d_in, const int* in_sizes, int n_in,
                              void* d_out, int out_size, void* d_ws, size_t ws_size,
                              hipStream_t stream) {
  (void)in_sizes; (void)n_in; (void)out_size; (void)ws_size;
  const float* x = (const float*)d_in[0];
  const float* P = (const float*)d_in[1];
  const float* p0 = (const float*)d_in[2];
  float* out = (float*)d_out;
  const size_t elems = (size_t)BB * TT * KK;

  // ws: alpha | beta (bf16, 64MB each).
  uint2* alpha = (uint2*)d_ws;
  uint2* beta = alpha + elems / 4;
  // d_out doubles as scratch until hmm_post overwrites it:
  // [pad 8KB][y bf16 64MB][C1 512KB]  (fwd prefetch overreads into C1,
  // bwd prefetch underreads into pad -- both allocated, never consumed).
  uint2* y = (uint2*)((char*)d_out + YPAD);
  float* C1 = (float*)((char*)d_out + YPAD + elems * 2);

  sig_pass2<<<(int)(BB * TT / 4), 256, 0, stream>>>(x, y, C1, P);
  hmm_recur2<<<2 * BB, 64, 0, stream>>>(y, C1, P, p0, alpha, beta);
  hmm_post<<<(BB * TT) / 4, 256, 0, stream>>>(
      (const __hip_bfloat16*)alpha, (const __hip_bfloat16*)beta, out);
}

// Round 3
// 352.095 us; speedup vs baseline: 1.5873x; 1.5873x over previous
//
#include <hip/hip_runtime.h>
#include <hip/hip_bf16.h>

// HMM forward-backward, B=128, T=1024, K=256.
// P = (diag-offd)*I + offd*J  -> (v@P)[j] = offd*sum(v) + (diag-offd)*v[j].
//
// R5: LDS-staged y transport (T3/T4 counted-vmcnt pattern, single-wave).
// R3 showed the compiler remats/sinks register prefetch of y rows (VGPR=32,
// ~250cyc/step stall); R4 showed volatile serializes (311us). Here y rows are
// staged in groups of 16 via async global_load_lds into a double-buffered LDS
// ring; ONE manual counted s_waitcnt vmcnt(24) per group (8 loads(g) oldest +
// 16 stores + 8 loads(g+1) newest = 32 outstanding; in-order retirement means
// <=24 <=> group g's loads landed; stores are NOT drained). The compiler
// cannot sink/remat global_load_lds, and ds_read latency (~120cy, pipelined)
// replaces L3 latency (~250cy, serial).
// Step math is bit-identical to R3 (passed, absmax 0.015625):
//   S_t = cd*R_t + C1[t]*S_{t-1},  R_t = sum_j(y_t * v_{t-1}),
//   C1[t] = offd*sum_j(y_t) precomputed in sig pass; rescale every 16 steps.

constexpr int BB = 128;
constexpr int TT = 1024;
constexpr int KK = 256;
constexpr size_t YPAD = 8192;

typedef unsigned long long u64t;

// ---------- DPP wave-64 sum reduction -> broadcast scalar ----------
template <int CTRL, int RM>
__device__ __forceinline__ float dpp_add(float v) {
  int t = __builtin_amdgcn_update_dpp(0, __float_as_int(v), CTRL, RM, 0xf, true);
  return v + __int_as_float(t);
}

__device__ __forceinline__ float wred_dpp(float v) {
  v = dpp_add<0x111, 0xf>(v);  // row_shr:1
  v = dpp_add<0x112, 0xf>(v);  // row_shr:2
  v = dpp_add<0x114, 0xf>(v);  // row_shr:4
  v = dpp_add<0x118, 0xf>(v);  // row_shr:8  -> lane 15 of each row = row sum
  v = dpp_add<0x142, 0xa>(v);  // row_bcast:15
  v = dpp_add<0x143, 0xc>(v);  // row_bcast:31 -> lane63 = total
  return __int_as_float(__builtin_amdgcn_readlane(__float_as_int(v), 63));
}

__device__ __forceinline__ float fsig(float x) {
  return __builtin_amdgcn_rcpf(1.0f + __expf(-x));
}

__device__ __forceinline__ unsigned cvtpk_bf16(float lo, float hi) {
  unsigned r;
  asm("v_cvt_pk_bf16_f32 %0, %1, %2" : "=v"(r) : "v"(lo), "v"(hi));
  return r;  // [15:0]=bf16(lo) [31:16]=bf16(hi), RNE
}
__device__ __forceinline__ float lo16f(unsigned u) { return __uint_as_float(u << 16); }
__device__ __forceinline__ float hi16f(unsigned u) { return __uint_as_float(u & 0xffff0000u); }
__device__ __forceinline__ float bf2f(unsigned short u) {
  return __uint_as_float((unsigned)u << 16);
}

// async global->LDS, 16B per lane (global addr per-lane, LDS dest = base+lane*16)
__device__ __forceinline__ void gl_lds16(const void* g, void* l) {
  __builtin_amdgcn_global_load_lds(
      (const __attribute__((address_space(1))) unsigned int*)g,
      (__attribute__((address_space(3))) unsigned int*)l, 16, 0, 0);
}

// ---------- pass 0: y = sigmoid(x) bf16 rows + C1[row] = offd*sum(y_row) ----
__global__ __launch_bounds__(256) void sig_pass2(const float* __restrict__ x,
                                                 uint2* __restrict__ y,
                                                 float* __restrict__ C1,
                                                 const float* __restrict__ P) {
  const int lane = threadIdx.x & 63;
  const size_t row = ((size_t)blockIdx.x << 2) | (threadIdx.x >> 6);  // b*TT+t
  const float4 v = reinterpret_cast<const float4*>(x)[row * 64 + lane];
  const unsigned p01 = cvtpk_bf16(fsig(v.x), fsig(v.y));
  const unsigned p23 = cvtpk_bf16(fsig(v.z), fsig(v.w));
  y[row * 64 + lane] = make_uint2(p01, p23);
  // sum the ROUNDED values so C1 matches what the recursion actually uses
  const float s = wred_dpp((lo16f(p01) + hi16f(p01)) + (lo16f(p23) + hi16f(p23)));
  if (lane == 0) C1[row] = P[1] * s;
}

// ---------- pass 1: forward/backward recursions ----------
__global__ __launch_bounds__(64, 1) void hmm_recur3(
    const uint2* __restrict__ y, const float* __restrict__ C1,
    const float* __restrict__ P, const float* __restrict__ p0,
    uint2* __restrict__ alpha, uint2* __restrict__ beta) {
  const int seq = blockIdx.x;   // 0..255
  const int lane = threadIdx.x; // 0..63
  const float diag = P[0];
  const float offd = P[1];
  const float cd = diag - offd;
  const float cod = offd;

  // double-buffered y staging: group = 16 rows = 8KB per half
  __shared__ u64t lbuf[2][16 * 64];

  const int b = (seq < BB) ? seq : (seq - BB);
  const char* ybytes = (const char*)(y + (size_t)b * TT * 64);
  const float* c1b = C1 + (size_t)b * TT;

  // stage aligned 16-row group grp into half h (8 x global_load_lds dwordx4)
  auto stage = [&](int grp, int h) {
    const char* gsrc = ybytes + (size_t)grp * 16 * 512 + (size_t)lane * 16;
    char* ldst = (char*)&lbuf[h][0];
#pragma unroll
    for (int i = 0; i < 8; ++i) gl_lds16(gsrc + i * 1024, ldst + i * 1024);
  };

  if (seq < BB) {
    // ---------------- forward: alpha (unnormalized, periodic rescale) -------
    uint2* ar = alpha + (size_t)b * TT * 64;

    const float4 pv = reinterpret_cast<const float4*>(p0)[lane];  // 1 vmem
    stage(0, 0);  // 8
    stage(1, 1);  // 8
    asm volatile("s_waitcnt vmcnt(8)" ::: "memory");  // p0 + group0 landed

    float v0, v1, v2, v3, S;
    {  // t = 0
      const u64t q = lbuf[0][lane];
      const unsigned qlo = (unsigned)q, qhi = (unsigned)(q >> 32);
      v0 = pv.x * lo16f(qlo); v1 = pv.y * hi16f(qlo);
      v2 = pv.z * lo16f(qhi); v3 = pv.w * hi16f(qhi);
      S = wred_dpp((v0 + v1) + (v2 + v3));
      ar[lane] = make_uint2(cvtpk_bf16(v0, v1), cvtpk_bf16(v2, v3));
    }

#define FSTEP(BC_, SL_, T_, C1V_)                                          \
  {                                                                        \
    const u64t q = (BC_)[(SL_)*64 + lane];                                 \
    const unsigned qlo = (unsigned)q, qhi = (unsigned)(q >> 32);           \
    const float y0 = lo16f(qlo), y1 = hi16f(qlo);                          \
    const float y2 = lo16f(qhi), y3 = hi16f(qhi);                          \
    const float R = wred_dpp((y0 * v0 + y1 * v1) + (y2 * v2 + y3 * v3));   \
    const float Sn = cd * R + (C1V_)*S;                                    \
    const float sc = cod * S;                                              \
    v0 = y0 * (cd * v0 + sc); v1 = y1 * (cd * v1 + sc);                    \
    v2 = y2 * (cd * v2 + sc); v3 = y3 * (cd * v3 + sc);                    \
    ar[(size_t)(T_)*64 + lane] =                                           \
        make_uint2(cvtpk_bf16(v0, v1), cvtpk_bf16(v2, v3));                \
    S = Sn;                                                                \
  }

    {  // peeled group 0: t = 1..15
      const u64t* bc = &lbuf[0][0];
#pragma unroll
      for (int i = 1; i <= 15; ++i) {
        const float c1v = c1b[i];
        FSTEP(bc, i, i, c1v);
      }
      const float rr = __builtin_amdgcn_rcpf(S);
      v0 *= rr; v1 *= rr; v2 *= rr; v3 *= rr; S = 1.0f;
    }

#pragma unroll 1
    for (int g = 1; g < 64; ++g) {   // steps t = 16g .. 16g+15
      float c1g[16];
#pragma unroll
      for (int j = 0; j < 16; ++j) c1g[j] = c1b[g * 16 + j];
      const int qn = (g < 63) ? (g + 1) : 63;   // g=63: dummy restage
      stage(qn, (g + 1) & 1);                   // dummy -> half 0 (not read)
      asm volatile("s_waitcnt vmcnt(24)" ::: "memory");  // group g landed
      const u64t* bc = &lbuf[g & 1][0];
      const int tb = g * 16;
#pragma unroll
      for (int i = 0; i < 16; ++i) { FSTEP(bc, i, tb + i, c1g[i]); }
      const float rr = __builtin_amdgcn_rcpf(S);
      v0 *= rr; v1 *= rr; v2 *= rr; v3 *= rr; S = 1.0f;
    }
#undef FSTEP
  } else {
    // ---------------- backward: beta (state m = y_{t+1} o beta_{t+1}) ------
    uint2* br = beta + (size_t)b * TT * 64;

    const uint2 yvL =
        reinterpret_cast<const uint2*>(ybytes)[(size_t)(TT - 1) * 64 + lane];
    stage(63, 1);  // rows 1008..1023
    stage(62, 0);  // rows 992..1007
    asm volatile("s_waitcnt vmcnt(8)" ::: "memory");  // yvL + group63 landed

    float m0 = lo16f(yvL.x), m1 = hi16f(yvL.x);
    float m2 = lo16f(yvL.y), m3 = hi16f(yvL.y);
    float S = wred_dpp((m0 + m1) + (m2 + m3));
    br[(size_t)(TT - 1) * 64 + lane] = make_uint2(0x3F803F80u, 0x3F803F80u);

#define BSTEP(BC_, SL_, T_, C1V_)                                          \
  {                                                                        \
    const u64t q = (BC_)[(SL_)*64 + lane];                                 \
    const unsigned qlo = (unsigned)q, qhi = (unsigned)(q >> 32);           \
    const float y0 = lo16f(qlo), y1 = hi16f(qlo);                          \
    const float y2 = lo16f(qhi), y3 = hi16f(qhi);                          \
    const float R = wred_dpp((y0 * m0 + y1 * m1) + (y2 * m2 + y3 * m3));   \
    const float Sn = cd * R + (C1V_)*S;                                    \
    const float sc = cod * S;                                              \
    const float h0 = cd * m0 + sc, h1 = cd * m1 + sc;                      \
    const float h2 = cd * m2 + sc, h3 = cd * m3 + sc;                      \
    br[(size_t)(T_)*64 + lane] =                                           \
        make_uint2(cvtpk_bf16(h0, h1), cvtpk_bf16(h2, h3));                \
    m0 = y0 * h0; m1 = y1 * h1; m2 = y2 * h2; m3 = y3 * h3;                \
    S = Sn;                                                                \
  }

    {  // peeled group 63: T = 1022..1008 (slots 14..0)
      const u64t* bc = &lbuf[1][0];
#pragma unroll
      for (int k = 0; k < 15; ++k) {
        const int T = 1022 - k;
        const float c1v = c1b[T];
        BSTEP(bc, 14 - k, T, c1v);
      }
      const float rr = __builtin_amdgcn_rcpf(S);
      m0 *= rr; m1 *= rr; m2 *= rr; m3 *= rr; S = 1.0f;
    }

#pragma unroll 1
    for (int g = 1; g < 64; ++g) {   // group q = 63-g: T = 16q+15 .. 16q
      const int q = 63 - g;
      float c1g[16];
#pragma unroll
      for (int j = 0; j < 16; ++j) c1g[j] = c1b[q * 16 + j];
      const int qn = (g < 63) ? (q - 1) : 1;   // g=63: dummy restage grp1
      stage(qn, qn & 1);                       // dummy -> half 1 (not read)
      asm volatile("s_waitcnt vmcnt(24)" ::: "memory");  // group q landed
      const u64t* bc = &lbuf[q & 1][0];
      const int tb = q * 16;
#pragma unroll
      for (int i = 0; i < 16; ++i) {  // T = tb+15-i, slot 15-i
        BSTEP(bc, 15 - i, tb + 15 - i, c1g[15 - i]);
      }
      const float rr = __builtin_amdgcn_rcpf(S);
      m0 *= rr; m1 *= rr; m2 *= rr; m3 *= rr; S = 1.0f;
    }
#undef BSTEP
  }
}

// ---------- pass 2: posterior = normalize(alpha*beta) ----------
__global__ __launch_bounds__(256) void hmm_post(
    const __hip_bfloat16* __restrict__ alpha,
    const __hip_bfloat16* __restrict__ beta, float* __restrict__ out) {
  const size_t gid = (size_t)blockIdx.x * 256 + threadIdx.x;
  const size_t row = gid >> 6;  // one wave per (b,t) row
  const int lane = (int)(gid & 63);
  const ushort4 av = reinterpret_cast<const ushort4*>(alpha)[row * 64 + lane];
  const ushort4 bv = reinterpret_cast<const ushort4*>(beta)[row * 64 + lane];
  const float g0 = bf2f(av.x) * bf2f(bv.x);
  const float g1 = bf2f(av.y) * bf2f(bv.y);
  const float g2 = bf2f(av.z) * bf2f(bv.z);
  const float g3 = bf2f(av.w) * bf2f(bv.w);
  const float s = wred_dpp((g0 + g1) + (g2 + g3));
  const float r = __builtin_amdgcn_rcpf(s);
  float4 o;
  o.x = g0 * r; o.y = g1 * r; o.z = g2 * r; o.w = g3 * r;
  reinterpret_cast<float4*>(out)[row * 64 + lane] = o;
}

extern "C" void kernel_launch(void* const* d_in, const int* in_sizes, int n_in,
                              void* d_out, int out_size, void* d_ws, size_t ws_size,
                              hipStream_t stream) {
  (void)in_sizes; (void)n_in; (void)out_size; (void)ws_size;
  const float* x = (const float*)d_in[0];
  const float* P = (const float*)d_in[1];
  const float* p0 = (const float*)d_in[2];
  float* out = (float*)d_out;
  const size_t elems = (size_t)BB * TT * KK;

  // ws: alpha | beta (bf16, 64MB each).
  uint2* alpha = (uint2*)d_ws;
  uint2* beta = alpha + elems / 4;
  // d_out doubles as scratch until hmm_post overwrites it:
  // [pad 8KB][y bf16 64MB][C1 512KB]
  uint2* y = (uint2*)((char*)d_out + YPAD);
  float* C1 = (float*)((char*)d_out + YPAD + elems * 2);

  sig_pass2<<<(int)(BB * TT / 4), 256, 0, stream>>>(x, y, C1, P);
  hmm_recur3<<<2 * BB, 64, 0, stream>>>(y, C1, P, p0, alpha, beta);
  hmm_post<<<(BB * TT) / 4, 256, 0, stream>>>(
      (const __hip_bfloat16*)alpha, (const __hip_bfloat16*)beta, out);
}

// Round 4
// 347.866 us; speedup vs baseline: 1.6066x; 1.0122x over previous
//
#include <hip/hip_runtime.h>
#include <hip/hip_bf16.h>

// HMM forward-backward, B=128, T=1024, K=256.
// P = (diag-offd)*I + offd*J  -> (v@P)[j] = offd*sum(v) + (diag-offd)*v[j].
//
// R6: kill the per-step load latency. Evidence: ~240-270 cyc/step constant
// across R1/R3/R5 despite three different y transports -> the stall is the
// per-step ds_read (~120cy lgkm) the compiler schedules right before use.
// Fix: per 16-row group, ONE hand-hoisted block of volatile-asm ds_reads
// (16x ds_read_b64 for y + 4x ds_read_b128 for C1) followed by a single
// s_waitcnt lgkmcnt(0) + sched_barrier(0) (rule #18), then 16 pure-VALU
// steps on register-resident data. C1 is staged via global_load_lds too, so
// the loop has ZERO compiler-generated lgkm ops (no counter mixing with our
// manual waits). Stage = 9 vmem ops/group (8 y + 1 c1); counted waits:
// prologue vmcnt(9), steady-state vmcnt(25) = 16 stores + 9 next-group.
// Step math bit-identical to R5 (passed, absmax 0.015625).

constexpr int BB = 128;
constexpr int TT = 1024;
constexpr int KK = 256;
constexpr size_t YPAD = 8192;

typedef unsigned long long u64t;
typedef unsigned int u32x4 __attribute__((ext_vector_type(4)));

// ---------- DPP wave-64 sum reduction -> broadcast scalar ----------
template <int CTRL, int RM>
__device__ __forceinline__ float dpp_add(float v) {
  int t = __builtin_amdgcn_update_dpp(0, __float_as_int(v), CTRL, RM, 0xf, true);
  return v + __int_as_float(t);
}

__device__ __forceinline__ float wred_dpp(float v) {
  v = dpp_add<0x111, 0xf>(v);  // row_shr:1
  v = dpp_add<0x112, 0xf>(v);  // row_shr:2
  v = dpp_add<0x114, 0xf>(v);  // row_shr:4
  v = dpp_add<0x118, 0xf>(v);  // row_shr:8  -> lane 15 of each row = row sum
  v = dpp_add<0x142, 0xa>(v);  // row_bcast:15
  v = dpp_add<0x143, 0xc>(v);  // row_bcast:31 -> lane63 = total
  return __int_as_float(__builtin_amdgcn_readlane(__float_as_int(v), 63));
}

__device__ __forceinline__ float fsig(float x) {
  return __builtin_amdgcn_rcpf(1.0f + __expf(-x));
}

__device__ __forceinline__ unsigned cvtpk_bf16(float lo, float hi) {
  unsigned r;
  asm("v_cvt_pk_bf16_f32 %0, %1, %2" : "=v"(r) : "v"(lo), "v"(hi));
  return r;  // [15:0]=bf16(lo) [31:16]=bf16(hi), RNE
}
__device__ __forceinline__ float lo16f(unsigned u) { return __uint_as_float(u << 16); }
__device__ __forceinline__ float hi16f(unsigned u) { return __uint_as_float(u & 0xffff0000u); }
__device__ __forceinline__ float bf2f(unsigned short u) {
  return __uint_as_float((unsigned)u << 16);
}

// async global->LDS (global addr per-lane; LDS dest = base + lane*size)
__device__ __forceinline__ void gl_lds16(const void* g, void* l) {
  __builtin_amdgcn_global_load_lds(
      (const __attribute__((address_space(1))) unsigned int*)g,
      (__attribute__((address_space(3))) unsigned int*)l, 16, 0, 0);
}
__device__ __forceinline__ void gl_lds4(const void* g, void* l) {
  __builtin_amdgcn_global_load_lds(
      (const __attribute__((address_space(1))) unsigned int*)g,
      (__attribute__((address_space(3))) unsigned int*)l, 4, 0, 0);
}

__device__ __forceinline__ unsigned lds_off(const void* p) {
  return (unsigned)(uintptr_t)(__attribute__((address_space(3))) const char*)p;
}

// ---------- pass 0: y = sigmoid(x) bf16 rows + C1[row] = offd*sum(y_row) ----
__global__ __launch_bounds__(256) void sig_pass2(const float* __restrict__ x,
                                                 uint2* __restrict__ y,
                                                 float* __restrict__ C1,
                                                 const float* __restrict__ P) {
  const int lane = threadIdx.x & 63;
  const size_t row = ((size_t)blockIdx.x << 2) | (threadIdx.x >> 6);  // b*TT+t
  const float4 v = reinterpret_cast<const float4*>(x)[row * 64 + lane];
  const unsigned p01 = cvtpk_bf16(fsig(v.x), fsig(v.y));
  const unsigned p23 = cvtpk_bf16(fsig(v.z), fsig(v.w));
  y[row * 64 + lane] = make_uint2(p01, p23);
  // sum the ROUNDED values so C1 matches what the recursion actually uses
  const float s = wred_dpp((lo16f(p01) + hi16f(p01)) + (lo16f(p23) + hi16f(p23)));
  if (lane == 0) C1[row] = P[1] * s;
}

// hoisted group read: 16 y rows (u64/lane) + 16 c1 floats, then one wait.
#define LOAD_GRP(YB_, CB_)                                                    \
  asm volatile("ds_read_b64 %0, %1 offset:0"    : "=v"(yr[0])  : "v"(YB_));   \
  asm volatile("ds_read_b64 %0, %1 offset:512"  : "=v"(yr[1])  : "v"(YB_));   \
  asm volatile("ds_read_b64 %0, %1 offset:1024" : "=v"(yr[2])  : "v"(YB_));   \
  asm volatile("ds_read_b64 %0, %1 offset:1536" : "=v"(yr[3])  : "v"(YB_));   \
  asm volatile("ds_read_b64 %0, %1 offset:2048" : "=v"(yr[4])  : "v"(YB_));   \
  asm volatile("ds_read_b64 %0, %1 offset:2560" : "=v"(yr[5])  : "v"(YB_));   \
  asm volatile("ds_read_b64 %0, %1 offset:3072" : "=v"(yr[6])  : "v"(YB_));   \
  asm volatile("ds_read_b64 %0, %1 offset:3584" : "=v"(yr[7])  : "v"(YB_));   \
  asm volatile("ds_read_b64 %0, %1 offset:4096" : "=v"(yr[8])  : "v"(YB_));   \
  asm volatile("ds_read_b64 %0, %1 offset:4608" : "=v"(yr[9])  : "v"(YB_));   \
  asm volatile("ds_read_b64 %0, %1 offset:5120" : "=v"(yr[10]) : "v"(YB_));   \
  asm volatile("ds_read_b64 %0, %1 offset:5632" : "=v"(yr[11]) : "v"(YB_));   \
  asm volatile("ds_read_b64 %0, %1 offset:6144" : "=v"(yr[12]) : "v"(YB_));   \
  asm volatile("ds_read_b64 %0, %1 offset:6656" : "=v"(yr[13]) : "v"(YB_));   \
  asm volatile("ds_read_b64 %0, %1 offset:7168" : "=v"(yr[14]) : "v"(YB_));   \
  asm volatile("ds_read_b64 %0, %1 offset:7680" : "=v"(yr[15]) : "v"(YB_));   \
  asm volatile("ds_read_b128 %0, %1 offset:0"   : "=v"(cq[0])  : "v"(CB_));   \
  asm volatile("ds_read_b128 %0, %1 offset:16"  : "=v"(cq[1])  : "v"(CB_));   \
  asm volatile("ds_read_b128 %0, %1 offset:32"  : "=v"(cq[2])  : "v"(CB_));   \
  asm volatile("ds_read_b128 %0, %1 offset:48"  : "=v"(cq[3])  : "v"(CB_));   \
  asm volatile("s_waitcnt lgkmcnt(0)" ::: "memory");                          \
  __builtin_amdgcn_sched_barrier(0);

#define C1F(J_) __uint_as_float(cq[(J_) >> 2][(J_)&3])

// ---------- pass 1: forward/backward recursions ----------
__global__ __launch_bounds__(64, 1) void hmm_recur4(
    const uint2* __restrict__ y, const float* __restrict__ C1,
    const float* __restrict__ P, const float* __restrict__ p0,
    uint2* __restrict__ alpha, uint2* __restrict__ beta) {
  const int seq = blockIdx.x;   // 0..255
  const int lane = threadIdx.x; // 0..63
  const float diag = P[0];
  const float offd = P[1];
  const float cd = diag - offd;
  const float cod = offd;

  // double-buffered staging: per half = 16 y rows (8KB) + 64 c1 floats (256B)
  __shared__ u64t lbuf[2][16 * 64];
  __shared__ float lc1[2][64];

  const int b = (seq < BB) ? seq : (seq - BB);
  const char* ybytes = (const char*)(y + (size_t)b * TT * 64);
  const float* c1b = C1 + (size_t)b * TT;

  // stage aligned 16-row group grp into half h: 8x lds16 (y) + 1x lds4 (c1)
  auto stage = [&](int grp, int h) {
    const char* gsrc = ybytes + (size_t)grp * 16 * 512 + (size_t)lane * 16;
    char* ldst = (char*)&lbuf[h][0];
#pragma unroll
    for (int i = 0; i < 8; ++i) gl_lds16(gsrc + i * 1024, ldst + i * 1024);
    gl_lds4(c1b + grp * 16 + lane, &lc1[h][0]);  // lanes 0-15 meaningful
  };

  const unsigned yb0 = lds_off(&lbuf[0][0]) + lane * 8;
  const unsigned yb1 = lds_off(&lbuf[1][0]) + lane * 8;
  const unsigned cb0 = lds_off(&lc1[0][0]);
  const unsigned cb1 = lds_off(&lc1[1][0]);

  u64t yr[16];
  u32x4 cq[4];

  if (seq < BB) {
    // ---------------- forward: alpha (unnormalized, periodic rescale) -------
    uint2* ar = alpha + (size_t)b * TT * 64;

    const float4 pv = reinterpret_cast<const float4*>(p0)[lane];  // 1 vmem
    stage(0, 0);  // 9
    stage(1, 1);  // 9
    asm volatile("s_waitcnt vmcnt(9)" ::: "memory");  // pv + group0 landed
    LOAD_GRP(yb0, cb0);

    float v0, v1, v2, v3, S;
    {  // t = 0 (row 0 = slot 0)
      const unsigned qlo = (unsigned)yr[0], qhi = (unsigned)(yr[0] >> 32);
      v0 = pv.x * lo16f(qlo); v1 = pv.y * hi16f(qlo);
      v2 = pv.z * lo16f(qhi); v3 = pv.w * hi16f(qhi);
      S = wred_dpp((v0 + v1) + (v2 + v3));
      ar[lane] = make_uint2(cvtpk_bf16(v0, v1), cvtpk_bf16(v2, v3));
    }

#define FSTEP(Q_, T_, C1V_)                                                \
  {                                                                        \
    const u64t q = (Q_);                                                   \
    const unsigned qlo = (unsigned)q, qhi = (unsigned)(q >> 32);           \
    const float y0 = lo16f(qlo), y1 = hi16f(qlo);                          \
    const float y2 = lo16f(qhi), y3 = hi16f(qhi);                          \
    const float R = wred_dpp((y0 * v0 + y1 * v1) + (y2 * v2 + y3 * v3));   \
    const float Sn = cd * R + (C1V_)*S;                                    \
    const float sc = cod * S;                                              \
    v0 = y0 * (cd * v0 + sc); v1 = y1 * (cd * v1 + sc);                    \
    v2 = y2 * (cd * v2 + sc); v3 = y3 * (cd * v3 + sc);                    \
    ar[(size_t)(T_)*64 + lane] =                                           \
        make_uint2(cvtpk_bf16(v0, v1), cvtpk_bf16(v2, v3));                \
    S = Sn;                                                                \
  }

    {  // peeled group 0: t = 1..15
#pragma unroll
      for (int i = 1; i <= 15; ++i) { FSTEP(yr[i], i, C1F(i)); }
      const float rr = __builtin_amdgcn_rcpf(S);
      v0 *= rr; v1 *= rr; v2 *= rr; v3 *= rr; S = 1.0f;
    }

#pragma unroll 1
    for (int g = 1; g < 64; ++g) {   // steps t = 16g .. 16g+15
      const int qn = (g < 63) ? (g + 1) : 63;   // g=63: dummy (half 0, unread)
      stage(qn, (g + 1) & 1);
      asm volatile("s_waitcnt vmcnt(25)" ::: "memory");  // group g landed
      const unsigned yb_ = (g & 1) ? yb1 : yb0;
      const unsigned cb_ = (g & 1) ? cb1 : cb0;
      LOAD_GRP(yb_, cb_);
      const int tb = g * 16;
#pragma unroll
      for (int i = 0; i < 16; ++i) { FSTEP(yr[i], tb + i, C1F(i)); }
      const float rr = __builtin_amdgcn_rcpf(S);
      v0 *= rr; v1 *= rr; v2 *= rr; v3 *= rr; S = 1.0f;
    }
#undef FSTEP
  } else {
    // ---------------- backward: beta (state m = y_{t+1} o beta_{t+1}) ------
    uint2* br = beta + (size_t)b * TT * 64;

    stage(63, 1);  // rows 1008..1023
    stage(62, 0);  // rows 992..1007
    asm volatile("s_waitcnt vmcnt(9)" ::: "memory");  // group 63 landed
    LOAD_GRP(yb1, cb1);

    float m0, m1, m2, m3, S;
    {  // t = 1023 (row 1023 = slot 15 of group 63)
      const unsigned qlo = (unsigned)yr[15], qhi = (unsigned)(yr[15] >> 32);
      m0 = lo16f(qlo); m1 = hi16f(qlo);
      m2 = lo16f(qhi); m3 = hi16f(qhi);
      S = wred_dpp((m0 + m1) + (m2 + m3));
      br[(size_t)(TT - 1) * 64 + lane] = make_uint2(0x3F803F80u, 0x3F803F80u);
    }

#define BSTEP(Q_, T_, C1V_)                                                \
  {                                                                        \
    const u64t q = (Q_);                                                   \
    const unsigned qlo = (unsigned)q, qhi = (unsigned)(q >> 32);           \
    const float y0 = lo16f(qlo), y1 = hi16f(qlo);                          \
    const float y2 = lo16f(qhi), y3 = hi16f(qhi);                          \
    const float R = wred_dpp((y0 * m0 + y1 * m1) + (y2 * m2 + y3 * m3));   \
    const float Sn = cd * R + (C1V_)*S;                                    \
    const float sc = cod * S;                                              \
    const float h0 = cd * m0 + sc, h1 = cd * m1 + sc;                      \
    const float h2 = cd * m2 + sc, h3 = cd * m3 + sc;                      \
    br[(size_t)(T_)*64 + lane] =                                           \
        make_uint2(cvtpk_bf16(h0, h1), cvtpk_bf16(h2, h3));                \
    m0 = y0 * h0; m1 = y1 * h1; m2 = y2 * h2; m3 = y3 * h3;                \
    S = Sn;                                                                \
  }

    {  // peeled group 63: T = 1022..1008 (slots 14..0)
#pragma unroll
      for (int k = 0; k < 15; ++k) { BSTEP(yr[14 - k], 1022 - k, C1F(14 - k)); }
      const float rr = __builtin_amdgcn_rcpf(S);
      m0 *= rr; m1 *= rr; m2 *= rr; m3 *= rr; S = 1.0f;
    }

#pragma unroll 1
    for (int g = 1; g < 64; ++g) {   // group q = 63-g: T = 16q+15 .. 16q
      const int q = 63 - g;
      const int qn = (g < 63) ? (q - 1) : 1;    // g=63: dummy (half 1, unread)
      stage(qn, qn & 1);
      asm volatile("s_waitcnt vmcnt(25)" ::: "memory");  // group q landed
      const unsigned yb_ = (q & 1) ? yb1 : yb0;
      const unsigned cb_ = (q & 1) ? cb1 : cb0;
      LOAD_GRP(yb_, cb_);
      const int tb = q * 16;
#pragma unroll
      for (int i = 0; i < 16; ++i) {  // T = tb+15-i, slot 15-i
        BSTEP(yr[15 - i], tb + 15 - i, C1F(15 - i));
      }
      const float rr = __builtin_amdgcn_rcpf(S);
      m0 *= rr; m1 *= rr; m2 *= rr; m3 *= rr; S = 1.0f;
    }
#undef BSTEP
  }
}

// ---------- pass 2: posterior = normalize(alpha*beta) ----------
__global__ __launch_bounds__(256) void hmm_post(
    const __hip_bfloat16* __restrict__ alpha,
    const __hip_bfloat16* __restrict__ beta, float* __restrict__ out) {
  const size_t gid = (size_t)blockIdx.x * 256 + threadIdx.x;
  const size_t row = gid >> 6;  // one wave per (b,t) row
  const int lane = (int)(gid & 63);
  const ushort4 av = reinterpret_cast<const ushort4*>(alpha)[row * 64 + lane];
  const ushort4 bv = reinterpret_cast<const ushort4*>(beta)[row * 64 + lane];
  const float g0 = bf2f(av.x) * bf2f(bv.x);
  const float g1 = bf2f(av.y) * bf2f(bv.y);
  const float g2 = bf2f(av.z) * bf2f(bv.z);
  const float g3 = bf2f(av.w) * bf2f(bv.w);
  const float s = wred_dpp((g0 + g1) + (g2 + g3));
  const float r = __builtin_amdgcn_rcpf(s);
  float4 o;
  o.x = g0 * r; o.y = g1 * r; o.z = g2 * r; o.w = g3 * r;
  reinterpret_cast<float4*>(out)[row * 64 + lane] = o;
}

extern "C" void kernel_launch(void* const* d_in, const int* in_sizes, int n_in,
                              void* d_out, int out_size, void* d_ws, size_t ws_size,
                              hipStream_t stream) {
  (void)in_sizes; (void)n_in; (void)out_size; (void)ws_size;
  const float* x = (const float*)d_in[0];
  const float* P = (const float*)d_in[1];
  const float* p0 = (const float*)d_in[2];
  float* out = (float*)d_out;
  const size_t elems = (size_t)BB * TT * KK;

  // ws: alpha | beta (bf16, 64MB each).
  uint2* alpha = (uint2*)d_ws;
  uint2* beta = alpha + elems / 4;
  // d_out doubles as scratch until hmm_post overwrites it:
  // [pad 8KB][y bf16 64MB][C1 512KB]
  uint2* y = (uint2*)((char*)d_out + YPAD);
  float* C1 = (float*)((char*)d_out + YPAD + elems * 2);

  sig_pass2<<<(int)(BB * TT / 4), 256, 0, stream>>>(x, y, C1, P);
  hmm_recur4<<<2 * BB, 64, 0, stream>>>(y, C1, P, p0, alpha, beta);
  hmm_post<<<(BB * TT) / 4, 256, 0, stream>>>(
      (const __hip_bfloat16*)alpha, (const __hip_bfloat16*)beta, out);
}